// Round 17
// baseline (164.688 us; speedup 1.0000x reference)
//
#include <hip/hip_runtime.h>
#include <hip/hip_bf16.h>

#define D_MODEL 1024
#define N_HEADS 16
#define DK 64
#define SEQ 2048
#define BATCH 4

typedef __attribute__((ext_vector_type(4))) float   f32v4;
typedef __attribute__((ext_vector_type(16))) float  f32v16;
typedef __attribute__((ext_vector_type(8))) __bf16  bf16x8;
typedef __attribute__((ext_vector_type(8))) unsigned short u16v8;
typedef __attribute__((ext_vector_type(4))) unsigned short u16v4;
typedef __attribute__((ext_vector_type(4))) unsigned int   u32v4;

#define QSCALE 0.18033688011112042f   // 0.125 * log2(e)
#define SMBIAS 12.0f                  // static softmax shift (log2 domain)

__device__ __forceinline__ int swz(int byte) {
    return byte ^ (((byte >> 7) & 7) << 4);
}

__device__ __forceinline__ unsigned short bfb(float f) {
    return __builtin_bit_cast(unsigned short, (__bf16)f);
}
__device__ __forceinline__ float bff(unsigned short u) {
    return (float)__builtin_bit_cast(__bf16, u);
}

__device__ __forceinline__ f32v4 mfma16(bf16x8 a, bf16x8 b, f32v4 c) {
    return __builtin_amdgcn_mfma_f32_16x16x32_bf16(a, b, c, 0, 0, 0);
}
__device__ __forceinline__ f32v16 mfma32(bf16x8 a, bf16x8 b, f32v16 c) {
    return __builtin_amdgcn_mfma_f32_32x32x16_bf16(a, b, c, 0, 0, 0);
}

#define GL2LDS16(gp, lp) \
    __builtin_amdgcn_global_load_lds((__attribute__((address_space(1))) const void*)(gp), \
                                     (__attribute__((address_space(3))) void*)(lp), 16, 0, 0)

#define VMWAIT(N) asm volatile("s_waitcnt vmcnt(" #N ")" ::: "memory")
#define LGKM0()   asm volatile("s_waitcnt lgkmcnt(0)" ::: "memory")

// ---------------------------------------------------------------------------
// Transpose+convert the four 1024x1024 fp32 weight matrices to bf16 Wt[n][k]
// ---------------------------------------------------------------------------
__global__ __launch_bounds__(256) void wtrans_kernel(const float* wq, const float* wk,
                                                     const float* wv, const float* wo,
                                                     unsigned short* wt) {
    __shared__ unsigned short ts[64][65];
    int bid = blockIdx.x;
    int mat = bid >> 8;            // 0..3
    int tile = bid & 255;          // 16x16 tiles of 64x64
    int kb = (tile >> 4) * 64;
    int nb = (tile & 15) * 64;
    const float* W = (mat == 0) ? wq : (mat == 1) ? wk : (mat == 2) ? wv : wo;
    unsigned short* out = wt + (size_t)mat * D_MODEL * D_MODEL;
    int t = threadIdx.x;
#pragma unroll
    for (int p = 0; p < 4; ++p) {
        int row = p * 16 + (t >> 4);
        int c0 = (t & 15) * 4;
        f32v4 v = *(const f32v4*)(W + (size_t)(kb + row) * D_MODEL + nb + c0);
#pragma unroll
        for (int j = 0; j < 4; ++j) ts[row][c0 + j] = bfb(v[j]);
    }
    __syncthreads();
#pragma unroll
    for (int p = 0; p < 2; ++p) {
        int n = p * 32 + (t >> 3);
        int k0 = (t & 7) * 8;
        u16v8 o;
#pragma unroll
        for (int j = 0; j < 8; ++j) o[j] = ts[k0 + j][n];
        *(u16v8*)(out + (size_t)(nb + n) * D_MODEL + kb + k0) = o;
    }
}

// ---------------------------------------------------------------------------
// Fused QKV projection v3: R15 geometry (BM=128,BN=128,BK=64; 256 threads,
// 4 waves; 2 blocks/CU) with a 3-deep B ring. Per iter t: issue A(t+1) fp32
// loads FIRST, then B(t+2) DMA. stage_write's implicit wait on A(t+1) drains
// all older VMEM — i.e. B(t+1), which now has TWO compute phases of cover —
// while B(t+2) stays in flight across the barrier (no explicit VMWAIT).
// LDS = A 2x16KB + B 3x16KB = 80KB -> exactly 2 blocks/CU.
// mat 0 emits Qh pre-scaled by QSCALE; mat 2 emits Vt [BH][DK][S] via swap.
// ---------------------------------------------------------------------------
__global__ __launch_bounds__(256, 2) void qkv_kernel(const float* __restrict__ qin,
                                                     const float* __restrict__ kin,
                                                     const float* __restrict__ vin,
                                                     const unsigned short* __restrict__ WT,
                                                     const float* __restrict__ bq,
                                                     const float* __restrict__ bk,
                                                     const float* __restrict__ bv,
                                                     unsigned short* __restrict__ Qh,
                                                     unsigned short* __restrict__ Kh,
                                                     unsigned short* __restrict__ Vtp) {
    __shared__ unsigned short lds_a[2][128 * 64];   // 2 x 16KB
    __shared__ unsigned short lds_b[3][128 * 64];   // 3 x 16KB
    int bid0 = blockIdx.x;
    int mat = bid0 >> 9;
    int bidl = bid0 & 511;
    const float* Af = (mat == 0) ? qin : (mat == 1) ? kin : vin;
    const unsigned short* Wt = WT + (size_t)mat * D_MODEL * D_MODEL;
    const float* bias = (mat == 0) ? bq : (mat == 1) ? bk : bv;
    bool vmode = (mat == 2);
    float osc = (mat == 0) ? QSCALE : 1.0f;

    int xcd = bidl & 7, blki = bidl >> 3;     // blki 0..63
    int mb = (xcd * 8 + (blki >> 3)) * 128;
    int nb = (blki & 7) * 128;
    int tid = threadIdx.x;
    int lane = tid & 63, wid = tid >> 6;      // 4 waves
    int l15 = lane & 15, g = lane >> 4;
    int r7 = lane >> 3, slot = lane & 7;
    int wr = wid >> 1, wc = wid & 1;
    int ssrc = (slot ^ r7) * 8;

    f32v4 acc[4][4] = {};

    int arow = tid >> 4;            // 0..15
    int acol = (tid & 15) * 4;      // fp32 col
    f32v4 a_stg[8];

    auto issueA = [&](int k0) {
#pragma unroll
        for (int j = 0; j < 8; ++j)
            a_stg[j] = *(const f32v4*)(Af + (size_t)(mb + j * 16 + arow) * D_MODEL + k0 + acol);
    };
    auto dmaB = [&](char* buf, int k0) {
#pragma unroll
        for (int ii = 0; ii < 4; ++ii) {
            int c = ii * 4 + wid;   // 16 chunks of 8 rows (1KB each)
            GL2LDS16(Wt + (size_t)(nb + c * 8 + r7) * D_MODEL + k0 + ssrc, buf + c * 1024);
        }
    };
    auto writeA = [&](char* buf) {
#pragma unroll
        for (int j = 0; j < 8; ++j) {
            u16v4 o;
#pragma unroll
            for (int e = 0; e < 4; ++e) o[e] = bfb(a_stg[j][e]);
            int row = j * 16 + arow;
            *(u16v4*)(buf + swz(row * 128 + (tid & 15) * 8)) = o;
        }
    };
    auto fragA = [&](char* buf, int row, int kk) -> bf16x8 {
        int sl = (kk * 4 + g) ^ (row & 7);
        return *(bf16x8*)(buf + row * 128 + sl * 16);
    };
    auto fragB = [&](char* buf, int row, int kk) -> bf16x8 {
        int sl = (kk * 4 + g) ^ (row & 7);
        return *(bf16x8*)(buf + row * 128 + sl * 16);
    };

    // prologue: A(0) + B(0),B(1); writeA drains everything (prologue only)
    issueA(0);
    dmaB((char*)lds_b[0], 0);
    dmaB((char*)lds_b[1], 64);
    writeA((char*)lds_a[0]);        // implicit wait on A(0) = youngest? A issued
                                    // first, so this waits A(0) only; drain rest:
    VMWAIT(0);                      // B(0),B(1) landed (prologue, uncovered anyway)
    LGKM0();
    __builtin_amdgcn_s_barrier();
    __builtin_amdgcn_sched_barrier(0);

    for (int t = 0; t < 16; ++t) {
        // issue order matters: A(t+1) FIRST (older), B(t+2) second (younger)
        if (t < 15) issueA((t + 1) * 64);
        if (t + 2 < 16) dmaB((char*)lds_b[(t + 2) % 3], (t + 2) * 64);
        char* pa = (char*)lds_a[t & 1];
        char* pb = (char*)lds_b[t % 3];
#pragma unroll
        for (int kk = 0; kk < 2; ++kk) {
            bf16x8 fa[4], fb[4];
            if (!vmode) {
#pragma unroll
                for (int mt = 0; mt < 4; ++mt) fa[mt] = fragA(pa, wr * 64 + mt * 16 + l15, kk);
#pragma unroll
                for (int nt = 0; nt < 4; ++nt) fb[nt] = fragB(pb, wc * 64 + nt * 16 + l15, kk);
            } else {
#pragma unroll
                for (int xx = 0; xx < 4; ++xx) fa[xx] = fragB(pb, wc * 64 + xx * 16 + l15, kk);
#pragma unroll
                for (int yy = 0; yy < 4; ++yy) fb[yy] = fragA(pa, wr * 64 + yy * 16 + l15, kk);
            }
            __builtin_amdgcn_s_setprio(1);
#pragma unroll
            for (int a = 0; a < 4; ++a)
#pragma unroll
                for (int b = 0; b < 4; ++b)
                    acc[a][b] = mfma16(fa[a], fb[b], acc[a][b]);
            __builtin_amdgcn_s_setprio(0);
        }
        if (t < 15) {
            writeA((char*)lds_a[(t + 1) & 1]);   // waits A(t+1) -> drains B(t+1)
                                                 // (older); B(t+2) stays in flight
            LGKM0();                             // A(t+1) ds_writes visible
            __builtin_amdgcn_s_barrier();
            __builtin_amdgcn_sched_barrier(0);
        }
    }

    if (!vmode) {
        unsigned short* out = (mat == 0) ? Qh : Kh;
#pragma unroll
        for (int nt = 0; nt < 4; ++nt) {
            int n = nb + wc * 64 + nt * 16 + l15;
            float bvv = bias[n];
#pragma unroll
            for (int mt = 0; mt < 4; ++mt) {
#pragma unroll
                for (int r = 0; r < 4; ++r) {
                    int m = mb + wr * 64 + mt * 16 + 4 * g + r;
                    float val = (acc[mt][nt][r] + bvv) * osc;
                    int bb = m >> 11, ss = m & 2047, hh = n >> 6, dd = n & 63;
                    out[(((size_t)(bb * N_HEADS + hh)) * SEQ + ss) * DK + dd] = bfb(val);
                }
            }
        }
    } else {
#pragma unroll
        for (int xx = 0; xx < 4; ++xx) {
#pragma unroll
            for (int r = 0; r < 4; ++r) {
                int n = nb + wc * 64 + xx * 16 + 4 * g + r;
                float bvv = bias[n];
                int hh = n >> 6, dd = n & 63;
#pragma unroll
                for (int yy = 0; yy < 4; ++yy) {
                    int tok = mb + wr * 64 + yy * 16 + l15;
                    int bb = tok >> 11, ss = tok & 2047;
                    float val = acc[xx][yy][r] + bvv;
                    Vtp[((size_t)(bb * N_HEADS + hh) * DK + dd) * SEQ + ss] = bfb(val);
                }
            }
        }
    }
}

// ---------------------------------------------------------------------------
// Output projection GEMM v2 (R16 — best measured): BM=128,BN=128,BK=64;
// 256 threads; 2-buffer double-buffer; pure global_load_lds; 2 blocks/CU.
// ---------------------------------------------------------------------------
__global__ __launch_bounds__(256, 2) void gemmo_kernel(const unsigned short* __restrict__ A,
                                                       const unsigned short* __restrict__ Wt,
                                                       const float* __restrict__ bias, float* Cptr) {
    __shared__ unsigned short lds[2][(128 + 128) * 64];   // per buf: A 16KB | B 16KB
    int bid0 = blockIdx.x;
    int xcd = bid0 & 7, blki = bid0 >> 3;     // blki 0..63
    int mb = (xcd * 8 + (blki >> 3)) * 128;
    int nb = (blki & 7) * 128;
    int tid = threadIdx.x;
    int lane = tid & 63, wid = tid >> 6;      // 4 waves
    int l15 = lane & 15, g = lane >> 4;
    int r7 = lane >> 3, slot = lane & 7;
    int wr = wid >> 1, wc = wid & 1;
    int ssrc = (slot ^ r7) * 8;

    f32v4 acc[4][4] = {};
    char* p0 = (char*)lds[0];
    char* p1 = (char*)lds[1];

    auto stage = [&](char* buf, int k0) {
#pragma unroll
        for (int ii = 0; ii < 4; ++ii) {
            int c = ii * 4 + wid;   // A: 16 chunks of 8 rows (1KB each)
            GL2LDS16(A + (size_t)(mb + c * 8 + r7) * D_MODEL + k0 + ssrc, buf + c * 1024);
        }
#pragma unroll
        for (int ii = 0; ii < 4; ++ii) {
            int c = ii * 4 + wid;   // B: 16 chunks
            GL2LDS16(Wt + (size_t)(nb + c * 8 + r7) * D_MODEL + k0 + ssrc, buf + 16384 + c * 1024);
        }
    };
    auto fragA = [&](char* buf, int row, int kk) -> bf16x8 {
        int sl = (kk * 4 + g) ^ (row & 7);
        return *(bf16x8*)(buf + row * 128 + sl * 16);
    };
    auto fragB = [&](char* buf, int row, int kk) -> bf16x8 {
        int sl = (kk * 4 + g) ^ (row & 7);
        return *(bf16x8*)(buf + 16384 + row * 128 + sl * 16);
    };

    stage(p0, 0);
    VMWAIT(0);
    __builtin_amdgcn_s_barrier();
    __builtin_amdgcn_sched_barrier(0);

    for (int t = 0; t < 16; ++t) {
        if (t < 15) stage(p1, (t + 1) * 64);
#pragma unroll
        for (int kk = 0; kk < 2; ++kk) {
            bf16x8 fa[4], fb[4];
#pragma unroll
            for (int mt = 0; mt < 4; ++mt) fa[mt] = fragA(p0, wr * 64 + mt * 16 + l15, kk);
#pragma unroll
            for (int nt = 0; nt < 4; ++nt) fb[nt] = fragB(p0, wc * 64 + nt * 16 + l15, kk);
            __builtin_amdgcn_s_setprio(1);
#pragma unroll
            for (int a = 0; a < 4; ++a)
#pragma unroll
                for (int b = 0; b < 4; ++b)
                    acc[a][b] = mfma16(fa[a], fb[b], acc[a][b]);
            __builtin_amdgcn_s_setprio(0);
        }
        if (t < 15) {
            VMWAIT(0);              // next tile's DMA landed (covered by compute)
            __builtin_amdgcn_s_barrier();
            __builtin_amdgcn_sched_barrier(0);
            char* tp = p0; p0 = p1; p1 = tp;
        }
    }

#pragma unroll
    for (int nt = 0; nt < 4; ++nt) {
        int n = nb + wc * 64 + nt * 16 + l15;
        float bv = bias[n];
#pragma unroll
        for (int mt = 0; mt < 4; ++mt) {
#pragma unroll
            for (int r = 0; r < 4; ++r) {
                int m = mb + wr * 64 + mt * 16 + 4 * g + r;
                Cptr[(size_t)m * D_MODEL + n] = acc[mt][nt][r] + bv;
            }
        }
    }
}

// ---------------------------------------------------------------------------
// Causal flash attention v7 (best measured): static-max softmax, swapped-QK,
// 2-buffer K/V with 1-deep prefetch + __syncthreads, 4 blocks/CU,
// per-CU-balanced tiles {15-x, 8+x, 7-x, x}; permlane32_swap P exchange.
// ---------------------------------------------------------------------------
__global__ __launch_bounds__(256, 4) void attn_kernel(const unsigned short* Qh, const unsigned short* Kh,
                                                      const unsigned short* Vt, unsigned short* ctxp) {
    __shared__ unsigned short k_lds[2][64 * 64];   // [key][d], swizzled content
    __shared__ unsigned short v_lds[2][64 * 64];   // [d][key], swizzled content
    int bid = blockIdx.x;
    int jq = bid >> 8, x = (bid >> 6) & 3;
    int tile = (jq == 0) ? (15 - x) : (jq == 1) ? (8 + x) : (jq == 2) ? (7 - x) : x;
    int bh = bid & 63;
    int bb = bh >> 4, hh = bh & 15;
    int tid = threadIdx.x;
    int wid = tid >> 6, lane = tid & 63;
    int l31 = lane & 31, hi = lane >> 5;
    int qw0 = tile * 128 + wid * 32;
    int qg = qw0 + l31;             // this lane's q-row
    const unsigned short* Qb = Qh + (size_t)bh * SEQ * DK;
    const unsigned short* Kb = Kh + (size_t)bh * SEQ * DK;
    const unsigned short* Vb = Vt + (size_t)bh * DK * SEQ;

    // Q B-fragments (already scaled by 0.125*log2e in qkv epilogue)
    bf16x8 qf[4];
#pragma unroll
    for (int ks = 0; ks < 4; ++ks)
        qf[ks] = *(const bf16x8*)(Qb + (size_t)qg * DK + ks * 16 + hi * 8);

    f32v16 o0 = {}, o1 = {};
    float lsum = 0.f;
    int n_kt = 2 * tile + 2;

    const int klane = 16 * (lane ^ (lane >> 3));            // swz folded into src
    const int vlane = 16 * ((lane & 7) ^ (lane >> 3));
    auto stage = [&](int bufi, int kg) {
        const char* kb0 = (const char*)(Kb + (size_t)kg * DK);
        const char* vb0 = (const char*)Vb + (size_t)kg * 2;
#pragma unroll
        for (int jj = 0; jj < 2; ++jj) {
            int base = wid * 2048 + jj * 1024;              // 1KB per instruction
            GL2LDS16(kb0 + base + klane, (char*)k_lds[bufi] + base);
            GL2LDS16(vb0 + (size_t)(wid * 16 + jj * 8 + (lane >> 3)) * (SEQ * 2) + vlane,
                     (char*)v_lds[bufi] + base);
        }
    };

#define PACK2(a, b) (((unsigned)bfb(b) << 16) | (unsigned)bfb(a))
#define PVSTEP(tt, r0, ks, vl)                                                          \
    {                                                                                   \
        unsigned x0 = PACK2(tt[r0 + 0], tt[r0 + 1]);                                    \
        unsigned x1 = PACK2(tt[r0 + 2], tt[r0 + 3]);                                    \
        unsigned x2 = PACK2(tt[r0 + 4], tt[r0 + 5]);                                    \
        unsigned x3 = PACK2(tt[r0 + 6], tt[r0 + 7]);                                    \
        asm volatile("v_permlane32_swap_b32 %0, %1" : "+v"(x0), "+v"(x2));              \
        asm volatile("v_permlane32_swap_b32 %0, %1" : "+v"(x1), "+v"(x3));              \
        u32v4 w;                                                                        \
        w[0] = x0;  w[1] = x1;  w[2] = x2;  w[3] = x3;                                  \
        bf16x8 paf = __builtin_bit_cast(bf16x8, w);                                     \
        bf16x8 vf0 = *(bf16x8*)((char*)(vl) + swz(l31 * 128 + ks * 32 + hi * 16));      \
        bf16x8 vf1 = *(bf16x8*)((char*)(vl) + swz((32 + l31) * 128 + ks * 32 + hi * 16)); \
        o0 = mfma32(paf, vf0, o0);                                                      \
        o1 = mfma32(paf, vf1, o1);                                                      \
    }

    auto compute_tile = [&](int ktb, const unsigned short* kl, const unsigned short* vl) {
        if (ktb > qw0 + 31) return;   // no live rows for this wave
        f32v16 t0 = {}, t1 = {};
        __builtin_amdgcn_s_setprio(1);
#pragma unroll
        for (int ks = 0; ks < 4; ++ks) {
            bf16x8 kf0 = *(bf16x8*)((char*)kl + swz(l31 * 128 + ks * 32 + hi * 16));
            bf16x8 kf1 = *(bf16x8*)((char*)kl + swz((32 + l31) * 128 + ks * 32 + hi * 16));
            t0 = mfma32(kf0, qf[ks], t0);
            t1 = mfma32(kf1, qf[ks], t1);
        }
        __builtin_amdgcn_s_setprio(0);
        if (ktb + 63 > qw0) {   // diagonal region: causal mask (-1e30 -> exp2 -> 0)
#pragma unroll
            for (int r = 0; r < 16; ++r) {
                int off = (r & 3) + 8 * (r >> 2) + 4 * hi;
                if (ktb + off > qg) t0[r] = -1e30f;
                if (ktb + 32 + off > qg) t1[r] = -1e30f;
            }
        }
        // static-max: P = exp2(s - SMBIAS); shift cancels in the final divide.
#pragma unroll
        for (int r = 0; r < 16; ++r) {
            t0[r] = __builtin_amdgcn_exp2f(t0[r] - SMBIAS);
            t1[r] = __builtin_amdgcn_exp2f(t1[r] - SMBIAS);
            lsum += t0[r] + t1[r];
        }
        __builtin_amdgcn_s_setprio(1);
        PVSTEP(t0, 0, 0, vl)
        PVSTEP(t0, 8, 1, vl)
        PVSTEP(t1, 0, 2, vl)
        PVSTEP(t1, 8, 3, vl)
        __builtin_amdgcn_s_setprio(0);
    };

    stage(0, 0);
    __syncthreads();            // drains prologue DMA (vmcnt 0) -> tile 0 ready
    int buf = 0;
    for (int kt = 0; kt < n_kt; ++kt) {
        if (kt + 1 < n_kt) stage(buf ^ 1, (kt + 1) * 64);   // issue DMA early
        compute_tile(kt * 64, k_lds[buf], v_lds[buf]);
        __syncthreads();        // drain DMA for tile kt+1 + release buf
        buf ^= 1;
    }

    // epilogue: combine half-row sums, redistribute 1/l, store ctx[b][q][h*64+d]
    float lt = lsum + __shfl_xor(lsum, 32);
    float rinv = 1.f / lt;
#pragma unroll
    for (int r = 0; r < 16; ++r) {
        int off = (r & 3) + 8 * (r >> 2) + 4 * hi;
        float rr = __shfl(rinv, off);
        int qq = qw0 + off;
        size_t base = ((size_t)(bb * SEQ + qq)) * D_MODEL + hh * DK;
        ctxp[base + l31] = bfb(o0[r] * rr);
        ctxp[base + 32 + l31] = bfb(o1[r] * rr);
    }
#undef PVSTEP
#undef PACK2
}

// ---------------------------------------------------------------------------
extern "C" void kernel_launch(void* const* d_in, const int* in_sizes, int n_in,
                              void* d_out, int out_size, void* d_ws, size_t ws_size,
                              hipStream_t stream) {
    const float* q  = (const float*)d_in[0];
    const float* k  = (const float*)d_in[1];
    const float* v  = (const float*)d_in[2];
    const float* wq = (const float*)d_in[4];
    const float* bq = (const float*)d_in[5];
    const float* wk = (const float*)d_in[6];
    const float* bk = (const float*)d_in[7];
    const float* wv = (const float*)d_in[8];
    const float* bv = (const float*)d_in[9];
    const float* wo = (const float*)d_in[10];
    const float* bo = (const float*)d_in[11];

    // workspace (ushort elems): Qh 8M | Kh 8M | Vt 8M | X/CTX 8M | WT 4M = 72 MB
    unsigned short* ws  = (unsigned short*)d_ws;
    const size_t M8 = (size_t)8 * 1024 * 1024;
    unsigned short* Qh = ws;
    unsigned short* Kh = ws + M8;
    unsigned short* Vt = ws + 2 * M8;
    unsigned short* X  = ws + 3 * M8;   // attention CTX (bf16)
    unsigned short* WT = ws + 4 * M8;
    const size_t MM = (size_t)D_MODEL * D_MODEL;

    wtrans_kernel<<<dim3(1024), dim3(256), 0, stream>>>(wq, wk, wv, wo, WT);
    qkv_kernel<<<dim3(1536), dim3(256), 0, stream>>>(q, k, v, WT, bq, bk, bv, Qh, Kh, Vt);
    attn_kernel<<<dim3(1024), dim3(256), 0, stream>>>(Qh, Kh, Vt, X);
    gemmo_kernel<<<dim3(512), dim3(256), 0, stream>>>(X, WT + 3 * MM, bo, (float*)d_out);
}

// Round 18
// 153.091 us; speedup vs baseline: 1.0758x; 1.0758x over previous
//
#include <hip/hip_runtime.h>
#include <hip/hip_bf16.h>

#define D_MODEL 1024
#define N_HEADS 16
#define DK 64
#define SEQ 2048
#define BATCH 4

typedef __attribute__((ext_vector_type(4))) float   f32v4;
typedef __attribute__((ext_vector_type(16))) float  f32v16;
typedef __attribute__((ext_vector_type(8))) __bf16  bf16x8;
typedef __attribute__((ext_vector_type(8))) unsigned short u16v8;
typedef __attribute__((ext_vector_type(4))) unsigned short u16v4;
typedef __attribute__((ext_vector_type(4))) unsigned int   u32v4;

#define QSCALE 0.18033688011112042f   // 0.125 * log2(e)
#define SMBIAS 12.0f                  // static softmax shift (log2 domain)

__device__ __forceinline__ int swz(int byte) {
    return byte ^ (((byte >> 7) & 7) << 4);
}

__device__ __forceinline__ unsigned short bfb(float f) {
    return __builtin_bit_cast(unsigned short, (__bf16)f);
}
__device__ __forceinline__ float bff(unsigned short u) {
    return (float)__builtin_bit_cast(__bf16, u);
}

__device__ __forceinline__ f32v4 mfma16(bf16x8 a, bf16x8 b, f32v4 c) {
    return __builtin_amdgcn_mfma_f32_16x16x32_bf16(a, b, c, 0, 0, 0);
}
__device__ __forceinline__ f32v16 mfma32(bf16x8 a, bf16x8 b, f32v16 c) {
    return __builtin_amdgcn_mfma_f32_32x32x16_bf16(a, b, c, 0, 0, 0);
}

#define GL2LDS16(gp, lp) \
    __builtin_amdgcn_global_load_lds((__attribute__((address_space(1))) const void*)(gp), \
                                     (__attribute__((address_space(3))) void*)(lp), 16, 0, 0)

#define VMWAIT(N) asm volatile("s_waitcnt vmcnt(" #N ")" ::: "memory")
#define LGKM0()   asm volatile("s_waitcnt lgkmcnt(0)" ::: "memory")

// ---------------------------------------------------------------------------
// Transpose+convert the four 1024x1024 fp32 weight matrices to bf16 Wt[n][k]
// ---------------------------------------------------------------------------
__global__ __launch_bounds__(256) void wtrans_kernel(const float* wq, const float* wk,
                                                     const float* wv, const float* wo,
                                                     unsigned short* wt) {
    __shared__ unsigned short ts[64][65];
    int bid = blockIdx.x;
    int mat = bid >> 8;            // 0..3
    int tile = bid & 255;          // 16x16 tiles of 64x64
    int kb = (tile >> 4) * 64;
    int nb = (tile & 15) * 64;
    const float* W = (mat == 0) ? wq : (mat == 1) ? wk : (mat == 2) ? wv : wo;
    unsigned short* out = wt + (size_t)mat * D_MODEL * D_MODEL;
    int t = threadIdx.x;
#pragma unroll
    for (int p = 0; p < 4; ++p) {
        int row = p * 16 + (t >> 4);
        int c0 = (t & 15) * 4;
        f32v4 v = *(const f32v4*)(W + (size_t)(kb + row) * D_MODEL + nb + c0);
#pragma unroll
        for (int j = 0; j < 4; ++j) ts[row][c0 + j] = bfb(v[j]);
    }
    __syncthreads();
#pragma unroll
    for (int p = 0; p < 2; ++p) {
        int n = p * 32 + (t >> 3);
        int k0 = (t & 7) * 8;
        u16v8 o;
#pragma unroll
        for (int j = 0; j < 8; ++j) o[j] = ts[k0 + j][n];
        *(u16v8*)(out + (size_t)(nb + n) * D_MODEL + kb + k0) = o;
    }
}

// ---------------------------------------------------------------------------
// Fused QKV projection v2 (R15/R16 — best measured): 1536 blocks (mat=bid>>9);
// BM=128,BN=128,BK=64; 256 threads (4 waves); 2-buffer double-buffer, one
// VMWAIT(0)+LGKM0+barrier per iter; fused fp32->bf16 coalesced A staging.
// LDS 64KB -> 2 blocks/CU (TLP covers the drain stalls).
// ---------------------------------------------------------------------------
__global__ __launch_bounds__(256, 2) void qkv_kernel(const float* __restrict__ qin,
                                                     const float* __restrict__ kin,
                                                     const float* __restrict__ vin,
                                                     const unsigned short* __restrict__ WT,
                                                     const float* __restrict__ bq,
                                                     const float* __restrict__ bk,
                                                     const float* __restrict__ bv,
                                                     unsigned short* __restrict__ Qh,
                                                     unsigned short* __restrict__ Kh,
                                                     unsigned short* __restrict__ Vtp) {
    __shared__ unsigned short lds[2][(128 + 128) * 64];   // per buf: A 16KB | B 16KB
    int bid0 = blockIdx.x;
    int mat = bid0 >> 9;
    int bidl = bid0 & 511;
    const float* Af = (mat == 0) ? qin : (mat == 1) ? kin : vin;
    const unsigned short* Wt = WT + (size_t)mat * D_MODEL * D_MODEL;
    const float* bias = (mat == 0) ? bq : (mat == 1) ? bk : bv;
    bool vmode = (mat == 2);
    float osc = (mat == 0) ? QSCALE : 1.0f;

    int xcd = bidl & 7, blki = bidl >> 3;     // blki 0..63
    int mb = (xcd * 8 + (blki >> 3)) * 128;
    int nb = (blki & 7) * 128;
    int tid = threadIdx.x;
    int lane = tid & 63, wid = tid >> 6;      // 4 waves
    int l15 = lane & 15, g = lane >> 4;
    int r7 = lane >> 3, slot = lane & 7;
    int wr = wid >> 1, wc = wid & 1;
    int ssrc = (slot ^ r7) * 8;

    f32v4 acc[4][4] = {};

    char* p0 = (char*)lds[0];
    char* p1 = (char*)lds[1];

    int arow = tid >> 4;            // 0..15
    int acol = (tid & 15) * 4;      // fp32 col
    f32v4 a_stg[8];

    auto stage_issue = [&](char* buf, int k0) {
#pragma unroll
        for (int j = 0; j < 8; ++j)
            a_stg[j] = *(const f32v4*)(Af + (size_t)(mb + j * 16 + arow) * D_MODEL + k0 + acol);
#pragma unroll
        for (int ii = 0; ii < 4; ++ii) {
            int c = ii * 4 + wid;   // 16 chunks of 8 rows (1KB each)
            GL2LDS16(Wt + (size_t)(nb + c * 8 + r7) * D_MODEL + k0 + ssrc, buf + 16384 + c * 1024);
        }
    };
    auto stage_write = [&](char* buf) {
#pragma unroll
        for (int j = 0; j < 8; ++j) {
            u16v4 o;
#pragma unroll
            for (int e = 0; e < 4; ++e) o[e] = bfb(a_stg[j][e]);
            int row = j * 16 + arow;
            *(u16v4*)(buf + swz(row * 128 + (tid & 15) * 8)) = o;
        }
    };
    auto fragA = [&](char* buf, int row, int kk) -> bf16x8 {
        int sl = (kk * 4 + g) ^ (row & 7);
        return *(bf16x8*)(buf + row * 128 + sl * 16);
    };
    auto fragB = [&](char* buf, int row, int kk) -> bf16x8 {
        int sl = (kk * 4 + g) ^ (row & 7);
        return *(bf16x8*)(buf + 16384 + row * 128 + sl * 16);
    };

    stage_issue(p0, 0);
    stage_write(p0);
    VMWAIT(0);
    LGKM0();
    __builtin_amdgcn_s_barrier();
    __builtin_amdgcn_sched_barrier(0);

    for (int t = 0; t < 16; ++t) {
        if (t < 15) stage_issue(p1, (t + 1) * 64);
#pragma unroll
        for (int kk = 0; kk < 2; ++kk) {
            bf16x8 fa[4], fb[4];
            if (!vmode) {
#pragma unroll
                for (int mt = 0; mt < 4; ++mt) fa[mt] = fragA(p0, wr * 64 + mt * 16 + l15, kk);
#pragma unroll
                for (int nt = 0; nt < 4; ++nt) fb[nt] = fragB(p0, wc * 64 + nt * 16 + l15, kk);
            } else {
#pragma unroll
                for (int xx = 0; xx < 4; ++xx) fa[xx] = fragB(p0, wc * 64 + xx * 16 + l15, kk);
#pragma unroll
                for (int yy = 0; yy < 4; ++yy) fb[yy] = fragA(p0, wr * 64 + yy * 16 + l15, kk);
            }
            __builtin_amdgcn_s_setprio(1);
#pragma unroll
            for (int a = 0; a < 4; ++a)
#pragma unroll
                for (int b = 0; b < 4; ++b)
                    acc[a][b] = mfma16(fa[a], fb[b], acc[a][b]);
            __builtin_amdgcn_s_setprio(0);
        }
        if (t < 15) {
            stage_write(p1);        // implicit wait on A(t+1) regs
            VMWAIT(0);              // B(t+1) DMA landed
            LGKM0();                // A(t+1) ds_writes landed
            __builtin_amdgcn_s_barrier();
            __builtin_amdgcn_sched_barrier(0);
            char* tp = p0; p0 = p1; p1 = tp;
        }
    }

    if (!vmode) {
        unsigned short* out = (mat == 0) ? Qh : Kh;
#pragma unroll
        for (int nt = 0; nt < 4; ++nt) {
            int n = nb + wc * 64 + nt * 16 + l15;
            float bvv = bias[n];
#pragma unroll
            for (int mt = 0; mt < 4; ++mt) {
#pragma unroll
                for (int r = 0; r < 4; ++r) {
                    int m = mb + wr * 64 + mt * 16 + 4 * g + r;
                    float val = (acc[mt][nt][r] + bvv) * osc;
                    int bb = m >> 11, ss = m & 2047, hh = n >> 6, dd = n & 63;
                    out[(((size_t)(bb * N_HEADS + hh)) * SEQ + ss) * DK + dd] = bfb(val);
                }
            }
        }
    } else {
#pragma unroll
        for (int xx = 0; xx < 4; ++xx) {
#pragma unroll
            for (int r = 0; r < 4; ++r) {
                int n = nb + wc * 64 + xx * 16 + 4 * g + r;
                float bvv = bias[n];
                int hh = n >> 6, dd = n & 63;
#pragma unroll
                for (int yy = 0; yy < 4; ++yy) {
                    int tok = mb + wr * 64 + yy * 16 + l15;
                    int bb = tok >> 11, ss = tok & 2047;
                    float val = acc[xx][yy][r] + bvv;
                    Vtp[((size_t)(bb * N_HEADS + hh) * DK + dd) * SEQ + ss] = bfb(val);
                }
            }
        }
    }
}

// ---------------------------------------------------------------------------
// Output projection GEMM v2 (R16 — best measured): BM=128,BN=128,BK=64;
// 256 threads; 2-buffer double-buffer; pure global_load_lds; 2 blocks/CU.
// ---------------------------------------------------------------------------
__global__ __launch_bounds__(256, 2) void gemmo_kernel(const unsigned short* __restrict__ A,
                                                       const unsigned short* __restrict__ Wt,
                                                       const float* __restrict__ bias, float* Cptr) {
    __shared__ unsigned short lds[2][(128 + 128) * 64];   // per buf: A 16KB | B 16KB
    int bid0 = blockIdx.x;
    int xcd = bid0 & 7, blki = bid0 >> 3;     // blki 0..63
    int mb = (xcd * 8 + (blki >> 3)) * 128;
    int nb = (blki & 7) * 128;
    int tid = threadIdx.x;
    int lane = tid & 63, wid = tid >> 6;      // 4 waves
    int l15 = lane & 15, g = lane >> 4;
    int r7 = lane >> 3, slot = lane & 7;
    int wr = wid >> 1, wc = wid & 1;
    int ssrc = (slot ^ r7) * 8;

    f32v4 acc[4][4] = {};
    char* p0 = (char*)lds[0];
    char* p1 = (char*)lds[1];

    auto stage = [&](char* buf, int k0) {
#pragma unroll
        for (int ii = 0; ii < 4; ++ii) {
            int c = ii * 4 + wid;   // A: 16 chunks of 8 rows (1KB each)
            GL2LDS16(A + (size_t)(mb + c * 8 + r7) * D_MODEL + k0 + ssrc, buf + c * 1024);
        }
#pragma unroll
        for (int ii = 0; ii < 4; ++ii) {
            int c = ii * 4 + wid;   // B: 16 chunks
            GL2LDS16(Wt + (size_t)(nb + c * 8 + r7) * D_MODEL + k0 + ssrc, buf + 16384 + c * 1024);
        }
    };
    auto fragA = [&](char* buf, int row, int kk) -> bf16x8 {
        int sl = (kk * 4 + g) ^ (row & 7);
        return *(bf16x8*)(buf + row * 128 + sl * 16);
    };
    auto fragB = [&](char* buf, int row, int kk) -> bf16x8 {
        int sl = (kk * 4 + g) ^ (row & 7);
        return *(bf16x8*)(buf + 16384 + row * 128 + sl * 16);
    };

    stage(p0, 0);
    VMWAIT(0);
    __builtin_amdgcn_s_barrier();
    __builtin_amdgcn_sched_barrier(0);

    for (int t = 0; t < 16; ++t) {
        if (t < 15) stage(p1, (t + 1) * 64);
#pragma unroll
        for (int kk = 0; kk < 2; ++kk) {
            bf16x8 fa[4], fb[4];
#pragma unroll
            for (int mt = 0; mt < 4; ++mt) fa[mt] = fragA(p0, wr * 64 + mt * 16 + l15, kk);
#pragma unroll
            for (int nt = 0; nt < 4; ++nt) fb[nt] = fragB(p0, wc * 64 + nt * 16 + l15, kk);
            __builtin_amdgcn_s_setprio(1);
#pragma unroll
            for (int a = 0; a < 4; ++a)
#pragma unroll
                for (int b = 0; b < 4; ++b)
                    acc[a][b] = mfma16(fa[a], fb[b], acc[a][b]);
            __builtin_amdgcn_s_setprio(0);
        }
        if (t < 15) {
            VMWAIT(0);              // next tile's DMA landed (covered by compute)
            __builtin_amdgcn_s_barrier();
            __builtin_amdgcn_sched_barrier(0);
            char* tp = p0; p0 = p1; p1 = tp;
        }
    }

#pragma unroll
    for (int nt = 0; nt < 4; ++nt) {
        int n = nb + wc * 64 + nt * 16 + l15;
        float bv = bias[n];
#pragma unroll
        for (int mt = 0; mt < 4; ++mt) {
#pragma unroll
            for (int r = 0; r < 4; ++r) {
                int m = mb + wr * 64 + mt * 16 + 4 * g + r;
                Cptr[(size_t)m * D_MODEL + n] = acc[mt][nt][r] + bv;
            }
        }
    }
}

// ---------------------------------------------------------------------------
// Causal flash attention v7 (best measured): static-max softmax, swapped-QK,
// 2-buffer K/V with 1-deep prefetch + __syncthreads, 4 blocks/CU,
// per-CU-balanced tiles {15-x, 8+x, 7-x, x}; permlane32_swap P exchange.
// ---------------------------------------------------------------------------
__global__ __launch_bounds__(256, 4) void attn_kernel(const unsigned short* Qh, const unsigned short* Kh,
                                                      const unsigned short* Vt, unsigned short* ctxp) {
    __shared__ unsigned short k_lds[2][64 * 64];   // [key][d], swizzled content
    __shared__ unsigned short v_lds[2][64 * 64];   // [d][key], swizzled content
    int bid = blockIdx.x;
    int jq = bid >> 8, x = (bid >> 6) & 3;
    int tile = (jq == 0) ? (15 - x) : (jq == 1) ? (8 + x) : (jq == 2) ? (7 - x) : x;
    int bh = bid & 63;
    int bb = bh >> 4, hh = bh & 15;
    int tid = threadIdx.x;
    int wid = tid >> 6, lane = tid & 63;
    int l31 = lane & 31, hi = lane >> 5;
    int qw0 = tile * 128 + wid * 32;
    int qg = qw0 + l31;             // this lane's q-row
    const unsigned short* Qb = Qh + (size_t)bh * SEQ * DK;
    const unsigned short* Kb = Kh + (size_t)bh * SEQ * DK;
    const unsigned short* Vb = Vt + (size_t)bh * DK * SEQ;

    // Q B-fragments (already scaled by 0.125*log2e in qkv epilogue)
    bf16x8 qf[4];
#pragma unroll
    for (int ks = 0; ks < 4; ++ks)
        qf[ks] = *(const bf16x8*)(Qb + (size_t)qg * DK + ks * 16 + hi * 8);

    f32v16 o0 = {}, o1 = {};
    float lsum = 0.f;
    int n_kt = 2 * tile + 2;

    const int klane = 16 * (lane ^ (lane >> 3));            // swz folded into src
    const int vlane = 16 * ((lane & 7) ^ (lane >> 3));
    auto stage = [&](int bufi, int kg) {
        const char* kb0 = (const char*)(Kb + (size_t)kg * DK);
        const char* vb0 = (const char*)Vb + (size_t)kg * 2;
#pragma unroll
        for (int jj = 0; jj < 2; ++jj) {
            int base = wid * 2048 + jj * 1024;              // 1KB per instruction
            GL2LDS16(kb0 + base + klane, (char*)k_lds[bufi] + base);
            GL2LDS16(vb0 + (size_t)(wid * 16 + jj * 8 + (lane >> 3)) * (SEQ * 2) + vlane,
                     (char*)v_lds[bufi] + base);
        }
    };

#define PACK2(a, b) (((unsigned)bfb(b) << 16) | (unsigned)bfb(a))
#define PVSTEP(tt, r0, ks, vl)                                                          \
    {                                                                                   \
        unsigned x0 = PACK2(tt[r0 + 0], tt[r0 + 1]);                                    \
        unsigned x1 = PACK2(tt[r0 + 2], tt[r0 + 3]);                                    \
        unsigned x2 = PACK2(tt[r0 + 4], tt[r0 + 5]);                                    \
        unsigned x3 = PACK2(tt[r0 + 6], tt[r0 + 7]);                                    \
        asm volatile("v_permlane32_swap_b32 %0, %1" : "+v"(x0), "+v"(x2));              \
        asm volatile("v_permlane32_swap_b32 %0, %1" : "+v"(x1), "+v"(x3));              \
        u32v4 w;                                                                        \
        w[0] = x0;  w[1] = x1;  w[2] = x2;  w[3] = x3;                                  \
        bf16x8 paf = __builtin_bit_cast(bf16x8, w);                                     \
        bf16x8 vf0 = *(bf16x8*)((char*)(vl) + swz(l31 * 128 + ks * 32 + hi * 16));      \
        bf16x8 vf1 = *(bf16x8*)((char*)(vl) + swz((32 + l31) * 128 + ks * 32 + hi * 16)); \
        o0 = mfma32(paf, vf0, o0);                                                      \
        o1 = mfma32(paf, vf1, o1);                                                      \
    }

    auto compute_tile = [&](int ktb, const unsigned short* kl, const unsigned short* vl) {
        if (ktb > qw0 + 31) return;   // no live rows for this wave
        f32v16 t0 = {}, t1 = {};
        __builtin_amdgcn_s_setprio(1);
#pragma unroll
        for (int ks = 0; ks < 4; ++ks) {
            bf16x8 kf0 = *(bf16x8*)((char*)kl + swz(l31 * 128 + ks * 32 + hi * 16));
            bf16x8 kf1 = *(bf16x8*)((char*)kl + swz((32 + l31) * 128 + ks * 32 + hi * 16));
            t0 = mfma32(kf0, qf[ks], t0);
            t1 = mfma32(kf1, qf[ks], t1);
        }
        __builtin_amdgcn_s_setprio(0);
        if (ktb + 63 > qw0) {   // diagonal region: causal mask (-1e30 -> exp2 -> 0)
#pragma unroll
            for (int r = 0; r < 16; ++r) {
                int off = (r & 3) + 8 * (r >> 2) + 4 * hi;
                if (ktb + off > qg) t0[r] = -1e30f;
                if (ktb + 32 + off > qg) t1[r] = -1e30f;
            }
        }
        // static-max: P = exp2(s - SMBIAS); shift cancels in the final divide.
#pragma unroll
        for (int r = 0; r < 16; ++r) {
            t0[r] = __builtin_amdgcn_exp2f(t0[r] - SMBIAS);
            t1[r] = __builtin_amdgcn_exp2f(t1[r] - SMBIAS);
            lsum += t0[r] + t1[r];
        }
        __builtin_amdgcn_s_setprio(1);
        PVSTEP(t0, 0, 0, vl)
        PVSTEP(t0, 8, 1, vl)
        PVSTEP(t1, 0, 2, vl)
        PVSTEP(t1, 8, 3, vl)
        __builtin_amdgcn_s_setprio(0);
    };

    stage(0, 0);
    __syncthreads();            // drains prologue DMA (vmcnt 0) -> tile 0 ready
    int buf = 0;
    for (int kt = 0; kt < n_kt; ++kt) {
        if (kt + 1 < n_kt) stage(buf ^ 1, (kt + 1) * 64);   // issue DMA early
        compute_tile(kt * 64, k_lds[buf], v_lds[buf]);
        __syncthreads();        // drain DMA for tile kt+1 + release buf
        buf ^= 1;
    }

    // epilogue: combine half-row sums, redistribute 1/l, store ctx[b][q][h*64+d]
    float lt = lsum + __shfl_xor(lsum, 32);
    float rinv = 1.f / lt;
#pragma unroll
    for (int r = 0; r < 16; ++r) {
        int off = (r & 3) + 8 * (r >> 2) + 4 * hi;
        float rr = __shfl(rinv, off);
        int qq = qw0 + off;
        size_t base = ((size_t)(bb * SEQ + qq)) * D_MODEL + hh * DK;
        ctxp[base + l31] = bfb(o0[r] * rr);
        ctxp[base + 32 + l31] = bfb(o1[r] * rr);
    }
#undef PVSTEP
#undef PACK2
}

// ---------------------------------------------------------------------------
extern "C" void kernel_launch(void* const* d_in, const int* in_sizes, int n_in,
                              void* d_out, int out_size, void* d_ws, size_t ws_size,
                              hipStream_t stream) {
    const float* q  = (const float*)d_in[0];
    const float* k  = (const float*)d_in[1];
    const float* v  = (const float*)d_in[2];
    const float* wq = (const float*)d_in[4];
    const float* bq = (const float*)d_in[5];
    const float* wk = (const float*)d_in[6];
    const float* bk = (const float*)d_in[7];
    const float* wv = (const float*)d_in[8];
    const float* bv = (const float*)d_in[9];
    const float* wo = (const float*)d_in[10];
    const float* bo = (const float*)d_in[11];

    // workspace (ushort elems): Qh 8M | Kh 8M | Vt 8M | X/CTX 8M | WT 4M = 72 MB
    unsigned short* ws  = (unsigned short*)d_ws;
    const size_t M8 = (size_t)8 * 1024 * 1024;
    unsigned short* Qh = ws;
    unsigned short* Kh = ws + M8;
    unsigned short* Vt = ws + 2 * M8;
    unsigned short* X  = ws + 3 * M8;   // attention CTX (bf16)
    unsigned short* WT = ws + 4 * M8;
    const size_t MM = (size_t)D_MODEL * D_MODEL;

    wtrans_kernel<<<dim3(1024), dim3(256), 0, stream>>>(wq, wk, wv, wo, WT);
    qkv_kernel<<<dim3(1536), dim3(256), 0, stream>>>(q, k, v, WT, bq, bk, bv, Qh, Kh, Vt);
    attn_kernel<<<dim3(1024), dim3(256), 0, stream>>>(Qh, Kh, Vt, X);
    gemmo_kernel<<<dim3(512), dim3(256), 0, stream>>>(X, WT + 3 * MM, bo, (float*)d_out);
}

// Round 19
// 152.952 us; speedup vs baseline: 1.0767x; 1.0009x over previous
//
#include <hip/hip_runtime.h>
#include <hip/hip_bf16.h>

#define D_MODEL 1024
#define N_HEADS 16
#define DK 64
#define SEQ 2048
#define BATCH 4

typedef __attribute__((ext_vector_type(4))) float   f32v4;
typedef __attribute__((ext_vector_type(16))) float  f32v16;
typedef __attribute__((ext_vector_type(8))) __bf16  bf16x8;
typedef __attribute__((ext_vector_type(8))) unsigned short u16v8;
typedef __attribute__((ext_vector_type(4))) unsigned short u16v4;
typedef __attribute__((ext_vector_type(4))) unsigned int   u32v4;

#define QSCALE 0.18033688011112042f   // 0.125 * log2(e)
#define SMBIAS 12.0f                  // static softmax shift (log2 domain)

__device__ __forceinline__ int swz(int byte) {
    return byte ^ (((byte >> 7) & 7) << 4);
}

__device__ __forceinline__ unsigned short bfb(float f) {
    return __builtin_bit_cast(unsigned short, (__bf16)f);
}
__device__ __forceinline__ float bff(unsigned short u) {
    return (float)__builtin_bit_cast(__bf16, u);
}

__device__ __forceinline__ f32v4 mfma16(bf16x8 a, bf16x8 b, f32v4 c) {
    return __builtin_amdgcn_mfma_f32_16x16x32_bf16(a, b, c, 0, 0, 0);
}
__device__ __forceinline__ f32v16 mfma32(bf16x8 a, bf16x8 b, f32v16 c) {
    return __builtin_amdgcn_mfma_f32_32x32x16_bf16(a, b, c, 0, 0, 0);
}

#define GL2LDS16(gp, lp) \
    __builtin_amdgcn_global_load_lds((__attribute__((address_space(1))) const void*)(gp), \
                                     (__attribute__((address_space(3))) void*)(lp), 16, 0, 0)

#define VMWAIT(N) asm volatile("s_waitcnt vmcnt(" #N ")" ::: "memory")
#define LGKM0()   asm volatile("s_waitcnt lgkmcnt(0)" ::: "memory")

// ---------------------------------------------------------------------------
// Transpose+convert the four 1024x1024 fp32 weight matrices to bf16 Wt[n][k]
// ---------------------------------------------------------------------------
__global__ __launch_bounds__(256) void wtrans_kernel(const float* wq, const float* wk,
                                                     const float* wv, const float* wo,
                                                     unsigned short* wt) {
    __shared__ unsigned short ts[64][65];
    int bid = blockIdx.x;
    int mat = bid >> 8;            // 0..3
    int tile = bid & 255;          // 16x16 tiles of 64x64
    int kb = (tile >> 4) * 64;
    int nb = (tile & 15) * 64;
    const float* W = (mat == 0) ? wq : (mat == 1) ? wk : (mat == 2) ? wv : wo;
    unsigned short* out = wt + (size_t)mat * D_MODEL * D_MODEL;
    int t = threadIdx.x;
#pragma unroll
    for (int p = 0; p < 4; ++p) {
        int row = p * 16 + (t >> 4);
        int c0 = (t & 15) * 4;
        f32v4 v = *(const f32v4*)(W + (size_t)(kb + row) * D_MODEL + nb + c0);
#pragma unroll
        for (int j = 0; j < 4; ++j) ts[row][c0 + j] = bfb(v[j]);
    }
    __syncthreads();
#pragma unroll
    for (int p = 0; p < 2; ++p) {
        int n = p * 32 + (t >> 3);
        int k0 = (t & 7) * 8;
        u16v8 o;
#pragma unroll
        for (int j = 0; j < 8; ++j) o[j] = ts[k0 + j][n];
        *(u16v8*)(out + (size_t)(nb + n) * D_MODEL + kb + k0) = o;
    }
}

// ---------------------------------------------------------------------------
// Fused QKV projection v2 (best measured): 1536 blocks (mat=bid>>9);
// BM=128,BN=128,BK=64; 256 threads (4 waves); 2-buffer double-buffer, one
// VMWAIT(0)+LGKM0+barrier per iter; fused fp32->bf16 coalesced A staging.
// LDS 64KB -> 2 blocks/CU (TLP covers the drain stalls).
// ---------------------------------------------------------------------------
__global__ __launch_bounds__(256, 2) void qkv_kernel(const float* __restrict__ qin,
                                                     const float* __restrict__ kin,
                                                     const float* __restrict__ vin,
                                                     const unsigned short* __restrict__ WT,
                                                     const float* __restrict__ bq,
                                                     const float* __restrict__ bk,
                                                     const float* __restrict__ bv,
                                                     unsigned short* __restrict__ Qh,
                                                     unsigned short* __restrict__ Kh,
                                                     unsigned short* __restrict__ Vtp) {
    __shared__ unsigned short lds[2][(128 + 128) * 64];   // per buf: A 16KB | B 16KB
    int bid0 = blockIdx.x;
    int mat = bid0 >> 9;
    int bidl = bid0 & 511;
    const float* Af = (mat == 0) ? qin : (mat == 1) ? kin : vin;
    const unsigned short* Wt = WT + (size_t)mat * D_MODEL * D_MODEL;
    const float* bias = (mat == 0) ? bq : (mat == 1) ? bk : bv;
    bool vmode = (mat == 2);
    float osc = (mat == 0) ? QSCALE : 1.0f;

    int xcd = bidl & 7, blki = bidl >> 3;     // blki 0..63
    int mb = (xcd * 8 + (blki >> 3)) * 128;
    int nb = (blki & 7) * 128;
    int tid = threadIdx.x;
    int lane = tid & 63, wid = tid >> 6;      // 4 waves
    int l15 = lane & 15, g = lane >> 4;
    int r7 = lane >> 3, slot = lane & 7;
    int wr = wid >> 1, wc = wid & 1;
    int ssrc = (slot ^ r7) * 8;

    f32v4 acc[4][4] = {};

    char* p0 = (char*)lds[0];
    char* p1 = (char*)lds[1];

    int arow = tid >> 4;            // 0..15
    int acol = (tid & 15) * 4;      // fp32 col
    f32v4 a_stg[8];

    auto stage_issue = [&](char* buf, int k0) {
#pragma unroll
        for (int j = 0; j < 8; ++j)
            a_stg[j] = *(const f32v4*)(Af + (size_t)(mb + j * 16 + arow) * D_MODEL + k0 + acol);
#pragma unroll
        for (int ii = 0; ii < 4; ++ii) {
            int c = ii * 4 + wid;   // 16 chunks of 8 rows (1KB each)
            GL2LDS16(Wt + (size_t)(nb + c * 8 + r7) * D_MODEL + k0 + ssrc, buf + 16384 + c * 1024);
        }
    };
    auto stage_write = [&](char* buf) {
#pragma unroll
        for (int j = 0; j < 8; ++j) {
            u16v4 o;
#pragma unroll
            for (int e = 0; e < 4; ++e) o[e] = bfb(a_stg[j][e]);
            int row = j * 16 + arow;
            *(u16v4*)(buf + swz(row * 128 + (tid & 15) * 8)) = o;
        }
    };
    auto fragA = [&](char* buf, int row, int kk) -> bf16x8 {
        int sl = (kk * 4 + g) ^ (row & 7);
        return *(bf16x8*)(buf + row * 128 + sl * 16);
    };
    auto fragB = [&](char* buf, int row, int kk) -> bf16x8 {
        int sl = (kk * 4 + g) ^ (row & 7);
        return *(bf16x8*)(buf + 16384 + row * 128 + sl * 16);
    };

    stage_issue(p0, 0);
    stage_write(p0);
    VMWAIT(0);
    LGKM0();
    __builtin_amdgcn_s_barrier();
    __builtin_amdgcn_sched_barrier(0);

    for (int t = 0; t < 16; ++t) {
        if (t < 15) stage_issue(p1, (t + 1) * 64);
#pragma unroll
        for (int kk = 0; kk < 2; ++kk) {
            bf16x8 fa[4], fb[4];
            if (!vmode) {
#pragma unroll
                for (int mt = 0; mt < 4; ++mt) fa[mt] = fragA(p0, wr * 64 + mt * 16 + l15, kk);
#pragma unroll
                for (int nt = 0; nt < 4; ++nt) fb[nt] = fragB(p0, wc * 64 + nt * 16 + l15, kk);
            } else {
#pragma unroll
                for (int xx = 0; xx < 4; ++xx) fa[xx] = fragB(p0, wc * 64 + xx * 16 + l15, kk);
#pragma unroll
                for (int yy = 0; yy < 4; ++yy) fb[yy] = fragA(p0, wr * 64 + yy * 16 + l15, kk);
            }
            __builtin_amdgcn_s_setprio(1);
#pragma unroll
            for (int a = 0; a < 4; ++a)
#pragma unroll
                for (int b = 0; b < 4; ++b)
                    acc[a][b] = mfma16(fa[a], fb[b], acc[a][b]);
            __builtin_amdgcn_s_setprio(0);
        }
        if (t < 15) {
            stage_write(p1);        // implicit wait on A(t+1) regs
            VMWAIT(0);              // B(t+1) DMA landed
            LGKM0();                // A(t+1) ds_writes landed
            __builtin_amdgcn_s_barrier();
            __builtin_amdgcn_sched_barrier(0);
            char* tp = p0; p0 = p1; p1 = tp;
        }
    }

    if (!vmode) {
        unsigned short* out = (mat == 0) ? Qh : Kh;
#pragma unroll
        for (int nt = 0; nt < 4; ++nt) {
            int n = nb + wc * 64 + nt * 16 + l15;
            float bvv = bias[n];
#pragma unroll
            for (int mt = 0; mt < 4; ++mt) {
#pragma unroll
                for (int r = 0; r < 4; ++r) {
                    int m = mb + wr * 64 + mt * 16 + 4 * g + r;
                    float val = (acc[mt][nt][r] + bvv) * osc;
                    int bb = m >> 11, ss = m & 2047, hh = n >> 6, dd = n & 63;
                    out[(((size_t)(bb * N_HEADS + hh)) * SEQ + ss) * DK + dd] = bfb(val);
                }
            }
        }
    } else {
#pragma unroll
        for (int xx = 0; xx < 4; ++xx) {
#pragma unroll
            for (int r = 0; r < 4; ++r) {
                int n = nb + wc * 64 + xx * 16 + 4 * g + r;
                float bvv = bias[n];
                int hh = n >> 6, dd = n & 63;
#pragma unroll
                for (int yy = 0; yy < 4; ++yy) {
                    int tok = mb + wr * 64 + yy * 16 + l15;
                    int bb = tok >> 11, ss = tok & 2047;
                    float val = acc[xx][yy][r] + bvv;
                    Vtp[((size_t)(bb * N_HEADS + hh) * DK + dd) * SEQ + ss] = bfb(val);
                }
            }
        }
    }
}

// ---------------------------------------------------------------------------
// Output projection GEMM v2 (best measured): BM=128,BN=128,BK=64;
// 256 threads; 2-buffer double-buffer; pure global_load_lds; 2 blocks/CU.
// ---------------------------------------------------------------------------
__global__ __launch_bounds__(256, 2) void gemmo_kernel(const unsigned short* __restrict__ A,
                                                       const unsigned short* __restrict__ Wt,
                                                       const float* __restrict__ bias, float* Cptr) {
    __shared__ unsigned short lds[2][(128 + 128) * 64];   // per buf: A 16KB | B 16KB
    int bid0 = blockIdx.x;
    int xcd = bid0 & 7, blki = bid0 >> 3;     // blki 0..63
    int mb = (xcd * 8 + (blki >> 3)) * 128;
    int nb = (blki & 7) * 128;
    int tid = threadIdx.x;
    int lane = tid & 63, wid = tid >> 6;      // 4 waves
    int l15 = lane & 15, g = lane >> 4;
    int r7 = lane >> 3, slot = lane & 7;
    int wr = wid >> 1, wc = wid & 1;
    int ssrc = (slot ^ r7) * 8;

    f32v4 acc[4][4] = {};
    char* p0 = (char*)lds[0];
    char* p1 = (char*)lds[1];

    auto stage = [&](char* buf, int k0) {
#pragma unroll
        for (int ii = 0; ii < 4; ++ii) {
            int c = ii * 4 + wid;   // A: 16 chunks of 8 rows (1KB each)
            GL2LDS16(A + (size_t)(mb + c * 8 + r7) * D_MODEL + k0 + ssrc, buf + c * 1024);
        }
#pragma unroll
        for (int ii = 0; ii < 4; ++ii) {
            int c = ii * 4 + wid;   // B: 16 chunks
            GL2LDS16(Wt + (size_t)(nb + c * 8 + r7) * D_MODEL + k0 + ssrc, buf + 16384 + c * 1024);
        }
    };
    auto fragA = [&](char* buf, int row, int kk) -> bf16x8 {
        int sl = (kk * 4 + g) ^ (row & 7);
        return *(bf16x8*)(buf + row * 128 + sl * 16);
    };
    auto fragB = [&](char* buf, int row, int kk) -> bf16x8 {
        int sl = (kk * 4 + g) ^ (row & 7);
        return *(bf16x8*)(buf + 16384 + row * 128 + sl * 16);
    };

    stage(p0, 0);
    VMWAIT(0);
    __builtin_amdgcn_s_barrier();
    __builtin_amdgcn_sched_barrier(0);

    for (int t = 0; t < 16; ++t) {
        if (t < 15) stage(p1, (t + 1) * 64);
#pragma unroll
        for (int kk = 0; kk < 2; ++kk) {
            bf16x8 fa[4], fb[4];
#pragma unroll
            for (int mt = 0; mt < 4; ++mt) fa[mt] = fragA(p0, wr * 64 + mt * 16 + l15, kk);
#pragma unroll
            for (int nt = 0; nt < 4; ++nt) fb[nt] = fragB(p0, wc * 64 + nt * 16 + l15, kk);
            __builtin_amdgcn_s_setprio(1);
#pragma unroll
            for (int a = 0; a < 4; ++a)
#pragma unroll
                for (int b = 0; b < 4; ++b)
                    acc[a][b] = mfma16(fa[a], fb[b], acc[a][b]);
            __builtin_amdgcn_s_setprio(0);
        }
        if (t < 15) {
            VMWAIT(0);              // next tile's DMA landed (covered by compute)
            __builtin_amdgcn_s_barrier();
            __builtin_amdgcn_sched_barrier(0);
            char* tp = p0; p0 = p1; p1 = tp;
        }
    }

#pragma unroll
    for (int nt = 0; nt < 4; ++nt) {
        int n = nb + wc * 64 + nt * 16 + l15;
        float bv = bias[n];
#pragma unroll
        for (int mt = 0; mt < 4; ++mt) {
#pragma unroll
            for (int r = 0; r < 4; ++r) {
                int m = mb + wr * 64 + mt * 16 + 4 * g + r;
                Cptr[(size_t)m * D_MODEL + n] = acc[mt][nt][r] + bv;
            }
        }
    }
}

// ---------------------------------------------------------------------------
// Causal flash attention v7 (best measured): static-max softmax, swapped-QK,
// 2-buffer K/V with 1-deep prefetch + __syncthreads, 4 blocks/CU,
// per-CU-balanced tiles {15-x, 8+x, 7-x, x}; permlane32_swap P exchange.
// ---------------------------------------------------------------------------
__global__ __launch_bounds__(256, 4) void attn_kernel(const unsigned short* Qh, const unsigned short* Kh,
                                                      const unsigned short* Vt, unsigned short* ctxp) {
    __shared__ unsigned short k_lds[2][64 * 64];   // [key][d], swizzled content
    __shared__ unsigned short v_lds[2][64 * 64];   // [d][key], swizzled content
    int bid = blockIdx.x;
    int jq = bid >> 8, x = (bid >> 6) & 3;
    int tile = (jq == 0) ? (15 - x) : (jq == 1) ? (8 + x) : (jq == 2) ? (7 - x) : x;
    int bh = bid & 63;
    int bb = bh >> 4, hh = bh & 15;
    int tid = threadIdx.x;
    int wid = tid >> 6, lane = tid & 63;
    int l31 = lane & 31, hi = lane >> 5;
    int qw0 = tile * 128 + wid * 32;
    int qg = qw0 + l31;             // this lane's q-row
    const unsigned short* Qb = Qh + (size_t)bh * SEQ * DK;
    const unsigned short* Kb = Kh + (size_t)bh * SEQ * DK;
    const unsigned short* Vb = Vt + (size_t)bh * DK * SEQ;

    // Q B-fragments (already scaled by 0.125*log2e in qkv epilogue)
    bf16x8 qf[4];
#pragma unroll
    for (int ks = 0; ks < 4; ++ks)
        qf[ks] = *(const bf16x8*)(Qb + (size_t)qg * DK + ks * 16 + hi * 8);

    f32v16 o0 = {}, o1 = {};
    float lsum = 0.f;
    int n_kt = 2 * tile + 2;

    const int klane = 16 * (lane ^ (lane >> 3));            // swz folded into src
    const int vlane = 16 * ((lane & 7) ^ (lane >> 3));
    auto stage = [&](int bufi, int kg) {
        const char* kb0 = (const char*)(Kb + (size_t)kg * DK);
        const char* vb0 = (const char*)Vb + (size_t)kg * 2;
#pragma unroll
        for (int jj = 0; jj < 2; ++jj) {
            int base = wid * 2048 + jj * 1024;              // 1KB per instruction
            GL2LDS16(kb0 + base + klane, (char*)k_lds[bufi] + base);
            GL2LDS16(vb0 + (size_t)(wid * 16 + jj * 8 + (lane >> 3)) * (SEQ * 2) + vlane,
                     (char*)v_lds[bufi] + base);
        }
    };

#define PACK2(a, b) (((unsigned)bfb(b) << 16) | (unsigned)bfb(a))
#define PVSTEP(tt, r0, ks, vl)                                                          \
    {                                                                                   \
        unsigned x0 = PACK2(tt[r0 + 0], tt[r0 + 1]);                                    \
        unsigned x1 = PACK2(tt[r0 + 2], tt[r0 + 3]);                                    \
        unsigned x2 = PACK2(tt[r0 + 4], tt[r0 + 5]);                                    \
        unsigned x3 = PACK2(tt[r0 + 6], tt[r0 + 7]);                                    \
        asm volatile("v_permlane32_swap_b32 %0, %1" : "+v"(x0), "+v"(x2));              \
        asm volatile("v_permlane32_swap_b32 %0, %1" : "+v"(x1), "+v"(x3));              \
        u32v4 w;                                                                        \
        w[0] = x0;  w[1] = x1;  w[2] = x2;  w[3] = x3;                                  \
        bf16x8 paf = __builtin_bit_cast(bf16x8, w);                                     \
        bf16x8 vf0 = *(bf16x8*)((char*)(vl) + swz(l31 * 128 + ks * 32 + hi * 16));      \
        bf16x8 vf1 = *(bf16x8*)((char*)(vl) + swz((32 + l31) * 128 + ks * 32 + hi * 16)); \
        o0 = mfma32(paf, vf0, o0);                                                      \
        o1 = mfma32(paf, vf1, o1);                                                      \
    }

    auto compute_tile = [&](int ktb, const unsigned short* kl, const unsigned short* vl) {
        if (ktb > qw0 + 31) return;   // no live rows for this wave
        f32v16 t0 = {}, t1 = {};
        __builtin_amdgcn_s_setprio(1);
#pragma unroll
        for (int ks = 0; ks < 4; ++ks) {
            bf16x8 kf0 = *(bf16x8*)((char*)kl + swz(l31 * 128 + ks * 32 + hi * 16));
            bf16x8 kf1 = *(bf16x8*)((char*)kl + swz((32 + l31) * 128 + ks * 32 + hi * 16));
            t0 = mfma32(kf0, qf[ks], t0);
            t1 = mfma32(kf1, qf[ks], t1);
        }
        __builtin_amdgcn_s_setprio(0);
        if (ktb + 63 > qw0) {   // diagonal region: causal mask (-1e30 -> exp2 -> 0)
#pragma unroll
            for (int r = 0; r < 16; ++r) {
                int off = (r & 3) + 8 * (r >> 2) + 4 * hi;
                if (ktb + off > qg) t0[r] = -1e30f;
                if (ktb + 32 + off > qg) t1[r] = -1e30f;
            }
        }
        // static-max: P = exp2(s - SMBIAS); shift cancels in the final divide.
#pragma unroll
        for (int r = 0; r < 16; ++r) {
            t0[r] = __builtin_amdgcn_exp2f(t0[r] - SMBIAS);
            t1[r] = __builtin_amdgcn_exp2f(t1[r] - SMBIAS);
            lsum += t0[r] + t1[r];
        }
        __builtin_amdgcn_s_setprio(1);
        PVSTEP(t0, 0, 0, vl)
        PVSTEP(t0, 8, 1, vl)
        PVSTEP(t1, 0, 2, vl)
        PVSTEP(t1, 8, 3, vl)
        __builtin_amdgcn_s_setprio(0);
    };

    stage(0, 0);
    __syncthreads();            // drains prologue DMA (vmcnt 0) -> tile 0 ready
    int buf = 0;
    for (int kt = 0; kt < n_kt; ++kt) {
        if (kt + 1 < n_kt) stage(buf ^ 1, (kt + 1) * 64);   // issue DMA early
        compute_tile(kt * 64, k_lds[buf], v_lds[buf]);
        __syncthreads();        // drain DMA for tile kt+1 + release buf
        buf ^= 1;
    }

    // epilogue: combine half-row sums, redistribute 1/l, store ctx[b][q][h*64+d]
    float lt = lsum + __shfl_xor(lsum, 32);
    float rinv = 1.f / lt;
#pragma unroll
    for (int r = 0; r < 16; ++r) {
        int off = (r & 3) + 8 * (r >> 2) + 4 * hi;
        float rr = __shfl(rinv, off);
        int qq = qw0 + off;
        size_t base = ((size_t)(bb * SEQ + qq)) * D_MODEL + hh * DK;
        ctxp[base + l31] = bfb(o0[r] * rr);
        ctxp[base + 32 + l31] = bfb(o1[r] * rr);
    }
#undef PVSTEP
#undef PACK2
}

// ---------------------------------------------------------------------------
extern "C" void kernel_launch(void* const* d_in, const int* in_sizes, int n_in,
                              void* d_out, int out_size, void* d_ws, size_t ws_size,
                              hipStream_t stream) {
    const float* q  = (const float*)d_in[0];
    const float* k  = (const float*)d_in[1];
    const float* v  = (const float*)d_in[2];
    const float* wq = (const float*)d_in[4];
    const float* bq = (const float*)d_in[5];
    const float* wk = (const float*)d_in[6];
    const float* bk = (const float*)d_in[7];
    const float* wv = (const float*)d_in[8];
    const float* bv = (const float*)d_in[9];
    const float* wo = (const float*)d_in[10];
    const float* bo = (const float*)d_in[11];

    // workspace (ushort elems): Qh 8M | Kh 8M | Vt 8M | X/CTX 8M | WT 4M = 72 MB
    unsigned short* ws  = (unsigned short*)d_ws;
    const size_t M8 = (size_t)8 * 1024 * 1024;
    unsigned short* Qh = ws;
    unsigned short* Kh = ws + M8;
    unsigned short* Vt = ws + 2 * M8;
    unsigned short* X  = ws + 3 * M8;   // attention CTX (bf16)
    unsigned short* WT = ws + 4 * M8;
    const size_t MM = (size_t)D_MODEL * D_MODEL;

    wtrans_kernel<<<dim3(1024), dim3(256), 0, stream>>>(wq, wk, wv, wo, WT);
    qkv_kernel<<<dim3(1536), dim3(256), 0, stream>>>(q, k, v, WT, bq, bk, bv, Qh, Kh, Vt);
    attn_kernel<<<dim3(1024), dim3(256), 0, stream>>>(Qh, Kh, Vt, X);
    gemmo_kernel<<<dim3(512), dim3(256), 0, stream>>>(X, WT + 3 * MM, bo, (float*)d_out);
}